// Round 5
// baseline (90.144 us; speedup 1.0000x reference)
//
#include <hip/hip_runtime.h>

#define B_ 64
#define H_ 384
#define W_ 384
#define C_ 3
#define PPT 4   // pixels per thread (one row, contiguous)

typedef float f32x4 __attribute__((ext_vector_type(4)));

__global__ __launch_bounds__(256) void bilerp_kernel(
    const float* __restrict__ images,
    const float* __restrict__ theta,
    float* __restrict__ out)
{
    const int total = B_ * H_ * W_;
    int tid = blockIdx.x * blockDim.x + threadIdx.x;
    int p = tid * PPT;
    if (p >= total) return;

    int j = p % W_;          // j in {0,4,...,380}; 4-px group never crosses a row
    int r = p / W_;
    int i = r % H_;
    int b = r / H_;

    const double STEP = 2.0 / 383.0;

    // ---- row-invariant (y) terms, computed once, bit-identical ops ----
    float ys = (i == H_ - 1) ? 1.0f : (float)((double)i * STEP - 1.0);
    const float* th = theta + b * 6;
    float th0 = th[0], th1 = th[1], th2 = th[2];
    float th3 = th[3], th4 = th[4], th5 = th[5];

    float t0_y = __fmul_rn(th1, ys);   // th1*ys term (identical op as reference)
    float t1_y = __fmul_rn(th4, ys);   // th4*ys term

    const float* img = images + (size_t)b * (H_ * W_ * C_);

    float res[PPT * C_];

    float taps_a[PPT][C_], taps_b[PPT][C_], taps_c[PPT][C_], taps_d[PPT][C_];
    float wa_[PPT], wb_[PPT], wc_[PPT], wd_[PPT];

    // ---- phase 1: addresses + issue all 16 gather loads ----
#pragma unroll
    for (int k = 0; k < PPT; ++k) {
        int jj = j + k;
        float xs = (jj == W_ - 1) ? 1.0f : (float)((double)jj * STEP - 1.0);

        // einsum: ((th0*xs) + (th1*ys)) + th2 — per-op f32, no contraction
        float t0 = __fadd_rn(__fadd_rn(__fmul_rn(th0, xs), t0_y), th2);
        float t1 = __fadd_rn(__fadd_rn(__fmul_rn(th3, xs), t1_y), th5);

        float x = __fmul_rn(__fadd_rn(t0, 1.0f), (float)(W_ * 0.5));
        float y = __fmul_rn(__fadd_rn(t1, 1.0f), (float)(H_ * 0.5));

        float fx = floorf(x);
        float fy = floorf(y);
        int x0 = min(max((int)fx, 0), W_ - 1);
        int x1 = min(max((int)fx + 1, 0), W_ - 1);
        int y0 = min(max((int)fy, 0), H_ - 1);
        int y1 = min(max((int)fy + 1, 0), H_ - 1);

        float xc = fminf(fmaxf(x, 0.0f), (float)(W_ - 1));
        float yc = fminf(fmaxf(y, 0.0f), (float)(H_ - 1));

        float x0f = (float)x0, x1f = (float)x1;
        float y0f = (float)y0, y1f = (float)y1;

        float wx0 = __fsub_rn(x1f, xc);
        float wx1 = __fsub_rn(xc, x0f);
        float wy0 = __fsub_rn(y1f, yc);
        float wy1 = __fsub_rn(yc, y0f);

        wa_[k] = __fmul_rn(wx0, wy0);
        wb_[k] = __fmul_rn(wx0, wy1);
        wc_[k] = __fmul_rn(wx1, wy0);
        wd_[k] = __fmul_rn(wx1, wy1);

        const float* pa = img + (y0 * W_ + x0) * C_;
        const float* pb = img + (y1 * W_ + x0) * C_;
        const float* pc = img + (y0 * W_ + x1) * C_;
        const float* pd = img + (y1 * W_ + x1) * C_;
#pragma unroll
        for (int c = 0; c < C_; ++c) {
            taps_a[k][c] = pa[c];
            taps_b[k][c] = pb[c];
            taps_c[k][c] = pc[c];
            taps_d[k][c] = pd[c];
        }
    }

    // ---- phase 2: weighted sums (compiler interleaves with load returns) ----
#pragma unroll
    for (int k = 0; k < PPT; ++k) {
#pragma unroll
        for (int c = 0; c < C_; ++c) {
            res[k * C_ + c] = __fadd_rn(
                __fadd_rn(
                    __fadd_rn(__fmul_rn(wa_[k], taps_a[k][c]),
                              __fmul_rn(wb_[k], taps_b[k][c])),
                    __fmul_rn(wc_[k], taps_c[k][c])),
                __fmul_rn(wd_[k], taps_d[k][c]));
        }
    }

    // ---- 48B contiguous store, 16B-aligned, nontemporal (never re-read) ----
    f32x4* o = (f32x4*)(out + (size_t)p * C_);
    f32x4 v0 = { res[0], res[1], res[2],  res[3]  };
    f32x4 v1 = { res[4], res[5], res[6],  res[7]  };
    f32x4 v2 = { res[8], res[9], res[10], res[11] };
    __builtin_nontemporal_store(v0, o + 0);
    __builtin_nontemporal_store(v1, o + 1);
    __builtin_nontemporal_store(v2, o + 2);
}

extern "C" void kernel_launch(void* const* d_in, const int* in_sizes, int n_in,
                              void* d_out, int out_size, void* d_ws, size_t ws_size,
                              hipStream_t stream) {
    const float* images = (const float*)d_in[0];
    const float* theta  = (const float*)d_in[1];
    float* out = (float*)d_out;

    const int total = B_ * H_ * W_;            // 9,437,184
    const int block = 256;
    const int grid = total / (block * PPT);    // 9216, exact

    bilerp_kernel<<<grid, block, 0, stream>>>(images, theta, out);
}

// Round 6
// 70.089 us; speedup vs baseline: 1.2861x; 1.2861x over previous
//
#include <hip/hip_runtime.h>

#define B_ 64
#define H_ 384
#define W_ 384
#define C_ 3
#define PPT 4   // pixels per thread (one row, contiguous)

typedef float f32x4 __attribute__((ext_vector_type(4)));

// 12-byte tap: one global_load_dwordx3 per tap
struct Tap { float v0, v1, v2; };

__global__ __launch_bounds__(256) void bilerp_kernel(
    const float* __restrict__ images,
    const float* __restrict__ theta,
    float* __restrict__ out)
{
    const int total = B_ * H_ * W_;

    // chunked XCD swizzle: grid=9216, 8 XCDs, 1152 blocks/XCD (bijective)
    int bid = blockIdx.x;
    int lbid = (bid & 7) * (9216 / 8) + (bid >> 3);

    int tid = lbid * blockDim.x + threadIdx.x;
    int p = tid * PPT;
    if (p >= total) return;

    int j = p % W_;          // j in {0,4,...,380}; group never crosses a row
    int r = p / W_;
    int i = r % H_;
    int b = r / H_;

    const double STEP = 2.0 / 383.0;

    // ---- row-invariant (y) terms, bit-identical ops ----
    float ys = (i == H_ - 1) ? 1.0f : (float)((double)i * STEP - 1.0);
    const float* th = theta + b * 6;
    float th0 = th[0], th1 = th[1], th2 = th[2];
    float th3 = th[3], th4 = th[4], th5 = th[5];

    float t0_y = __fmul_rn(th1, ys);
    float t1_y = __fmul_rn(th4, ys);

    const float* img = images + (size_t)b * (H_ * W_ * C_);

    Tap ta[PPT], tb[PPT], tc[PPT], td[PPT];
    float wa_[PPT], wb_[PPT], wc_[PPT], wd_[PPT];

    // ---- phase 1: addresses + issue all 16 dwordx3 gather loads ----
#pragma unroll
    for (int k = 0; k < PPT; ++k) {
        int jj = j + k;
        float xs = (jj == W_ - 1) ? 1.0f : (float)((double)jj * STEP - 1.0);

        // einsum: ((th0*xs) + (th1*ys)) + th2 — per-op f32, no contraction
        float t0 = __fadd_rn(__fadd_rn(__fmul_rn(th0, xs), t0_y), th2);
        float t1 = __fadd_rn(__fadd_rn(__fmul_rn(th3, xs), t1_y), th5);

        float x = __fmul_rn(__fadd_rn(t0, 1.0f), (float)(W_ * 0.5));
        float y = __fmul_rn(__fadd_rn(t1, 1.0f), (float)(H_ * 0.5));

        float fx = floorf(x);
        float fy = floorf(y);
        int x0 = min(max((int)fx, 0), W_ - 1);
        int x1 = min(max((int)fx + 1, 0), W_ - 1);
        int y0 = min(max((int)fy, 0), H_ - 1);
        int y1 = min(max((int)fy + 1, 0), H_ - 1);

        float xc = fminf(fmaxf(x, 0.0f), (float)(W_ - 1));
        float yc = fminf(fmaxf(y, 0.0f), (float)(H_ - 1));

        float x0f = (float)x0, x1f = (float)x1;
        float y0f = (float)y0, y1f = (float)y1;

        float wx0 = __fsub_rn(x1f, xc);
        float wx1 = __fsub_rn(xc, x0f);
        float wy0 = __fsub_rn(y1f, yc);
        float wy1 = __fsub_rn(yc, y0f);

        wa_[k] = __fmul_rn(wx0, wy0);
        wb_[k] = __fmul_rn(wx0, wy1);
        wc_[k] = __fmul_rn(wx1, wy0);
        wd_[k] = __fmul_rn(wx1, wy1);

        const Tap* pa = (const Tap*)(img + (y0 * W_ + x0) * C_);
        const Tap* pb = (const Tap*)(img + (y1 * W_ + x0) * C_);
        const Tap* pc = (const Tap*)(img + (y0 * W_ + x1) * C_);
        const Tap* pd = (const Tap*)(img + (y1 * W_ + x1) * C_);
        ta[k] = *pa;
        tb[k] = *pb;
        tc[k] = *pc;
        td[k] = *pd;
    }

    // ---- phase 2: weighted sums, per-op rounded f32 ----
    float res[PPT * C_];
#pragma unroll
    for (int k = 0; k < PPT; ++k) {
        const float A[3] = { ta[k].v0, ta[k].v1, ta[k].v2 };
        const float Bv[3] = { tb[k].v0, tb[k].v1, tb[k].v2 };
        const float Cv[3] = { tc[k].v0, tc[k].v1, tc[k].v2 };
        const float D[3] = { td[k].v0, td[k].v1, td[k].v2 };
#pragma unroll
        for (int c = 0; c < C_; ++c) {
            res[k * C_ + c] = __fadd_rn(
                __fadd_rn(
                    __fadd_rn(__fmul_rn(wa_[k], A[c]),
                              __fmul_rn(wb_[k], Bv[c])),
                    __fmul_rn(wc_[k], Cv[c])),
                __fmul_rn(wd_[k], D[c]));
        }
    }

    // ---- 48B contiguous store, 16B-aligned, NORMAL cached stores ----
    f32x4* o = (f32x4*)(out + (size_t)p * C_);
    f32x4 v0 = { res[0], res[1], res[2],  res[3]  };
    f32x4 v1 = { res[4], res[5], res[6],  res[7]  };
    f32x4 v2 = { res[8], res[9], res[10], res[11] };
    o[0] = v0;
    o[1] = v1;
    o[2] = v2;
}

extern "C" void kernel_launch(void* const* d_in, const int* in_sizes, int n_in,
                              void* d_out, int out_size, void* d_ws, size_t ws_size,
                              hipStream_t stream) {
    const float* images = (const float*)d_in[0];
    const float* theta  = (const float*)d_in[1];
    float* out = (float*)d_out;

    const int total = B_ * H_ * W_;            // 9,437,184
    const int block = 256;
    const int grid = total / (block * PPT);    // 9216, exact

    bilerp_kernel<<<grid, block, 0, stream>>>(images, theta, out);
}

// Round 7
// 51.611 us; speedup vs baseline: 1.7466x; 1.3580x over previous
//
#include <hip/hip_runtime.h>

#define B_ 64
#define H_ 384
#define W_ 384
#define C_ 3
#define K_ 4            // pixels per thread (stride 64 within the wave's chunk)
#define IMG_PX (H_ * W_)          // 147456, divisible by 256
#define PX_PER_BLOCK 1024         // 256 threads * 4 px
#define GRID 9216                 // 9.4M / 1024

// 12-byte tap: one global_load_dwordx3
struct Tap { float v0, v1, v2; };

__global__ __launch_bounds__(256, 2) void bilerp_kernel(
    const float* __restrict__ images,
    const float* __restrict__ theta,
    float* __restrict__ out)
{
    // bijective chunked XCD swizzle (GRID % 8 == 0): input stays L3-resident
    int bid = blockIdx.x;
    int lbid = (bid & 7) * (GRID / 8) + (bid >> 3);

    int wave = threadIdx.x >> 6;
    int lane = threadIdx.x & 63;
    int wbase = lbid * PX_PER_BLOCK + wave * 256;   // wave's 256-px chunk base

    // whole wave chunk lies in one image (IMG_PX % 256 == 0)
    int b = wbase / IMG_PX;
    int qbase = wbase - b * IMG_PX;

    const float* th = theta + b * 6;
    float th0 = th[0], th1 = th[1], th2 = th[2];
    float th3 = th[3], th4 = th[4], th5 = th[5];
    const float* img = images + (size_t)b * (IMG_PX * C_);

    const double STEP = 2.0 / 383.0;

    float wa_[K_], wb_[K_], wc_[K_], wd_[K_];
    Tap ta[K_], tb[K_], tc[K_], td[K_];
    int pq[K_];

    // ---- phase 1: all addresses + all 16 gather loads issued ----
#pragma unroll
    for (int k = 0; k < K_; ++k) {
        int q = qbase + k * 64 + lane;     // pixel index within image
        pq[k] = q;
        int i = q / W_;
        int j = q - i * W_;

        // numpy f32 linspace: f64 (k*step - 1) then cast; endpoint exact
        float xs = (j == W_ - 1) ? 1.0f : (float)((double)j * STEP - 1.0);
        float ys = (i == H_ - 1) ? 1.0f : (float)((double)i * STEP - 1.0);

        // einsum: ((th0*xs) + (th1*ys)) + th2 — per-op f32, no contraction
        float t0 = __fadd_rn(__fadd_rn(__fmul_rn(th0, xs), __fmul_rn(th1, ys)), th2);
        float t1 = __fadd_rn(__fadd_rn(__fmul_rn(th3, xs), __fmul_rn(th4, ys)), th5);

        float x = __fmul_rn(__fadd_rn(t0, 1.0f), (float)(W_ * 0.5));
        float y = __fmul_rn(__fadd_rn(t1, 1.0f), (float)(H_ * 0.5));

        float fx = floorf(x);
        float fy = floorf(y);
        int x0 = min(max((int)fx, 0), W_ - 1);
        int x1 = min(max((int)fx + 1, 0), W_ - 1);
        int y0 = min(max((int)fy, 0), H_ - 1);
        int y1 = min(max((int)fy + 1, 0), H_ - 1);

        float xc = fminf(fmaxf(x, 0.0f), (float)(W_ - 1));
        float yc = fminf(fmaxf(y, 0.0f), (float)(H_ - 1));

        float x0f = (float)x0, x1f = (float)x1;
        float y0f = (float)y0, y1f = (float)y1;

        float wx0 = __fsub_rn(x1f, xc);
        float wx1 = __fsub_rn(xc, x0f);
        float wy0 = __fsub_rn(y1f, yc);
        float wy1 = __fsub_rn(yc, y0f);

        wa_[k] = __fmul_rn(wx0, wy0);
        wb_[k] = __fmul_rn(wx0, wy1);
        wc_[k] = __fmul_rn(wx1, wy0);
        wd_[k] = __fmul_rn(wx1, wy1);

        ta[k] = *(const Tap*)(img + (y0 * W_ + x0) * C_);
        tb[k] = *(const Tap*)(img + (y1 * W_ + x0) * C_);
        tc[k] = *(const Tap*)(img + (y0 * W_ + x1) * C_);
        td[k] = *(const Tap*)(img + (y1 * W_ + x1) * C_);
    }

    // ---- phase 2: weighted sums + per-k dwordx3 store (12B/lane contiguous) ----
    float* outb = out + (size_t)b * (IMG_PX * C_);
#pragma unroll
    for (int k = 0; k < K_; ++k) {
        float r0 = __fadd_rn(
            __fadd_rn(
                __fadd_rn(__fmul_rn(wa_[k], ta[k].v0), __fmul_rn(wb_[k], tb[k].v0)),
                __fmul_rn(wc_[k], tc[k].v0)),
            __fmul_rn(wd_[k], td[k].v0));
        float r1 = __fadd_rn(
            __fadd_rn(
                __fadd_rn(__fmul_rn(wa_[k], ta[k].v1), __fmul_rn(wb_[k], tb[k].v1)),
                __fmul_rn(wc_[k], tc[k].v1)),
            __fmul_rn(wd_[k], td[k].v1));
        float r2 = __fadd_rn(
            __fadd_rn(
                __fadd_rn(__fmul_rn(wa_[k], ta[k].v2), __fmul_rn(wb_[k], tb[k].v2)),
                __fmul_rn(wc_[k], tc[k].v2)),
            __fmul_rn(wd_[k], td[k].v2));

        Tap* o = (Tap*)(outb + (size_t)pq[k] * C_);
        Tap v = { r0, r1, r2 };
        *o = v;
    }
}

extern "C" void kernel_launch(void* const* d_in, const int* in_sizes, int n_in,
                              void* d_out, int out_size, void* d_ws, size_t ws_size,
                              hipStream_t stream) {
    const float* images = (const float*)d_in[0];
    const float* theta  = (const float*)d_in[1];
    float* out = (float*)d_out;

    bilerp_kernel<<<GRID, 256, 0, stream>>>(images, theta, out);
}

// Round 8
// 48.429 us; speedup vs baseline: 1.8614x; 1.0657x over previous
//
#include <hip/hip_runtime.h>

#define B_ 64
#define H_ 384
#define W_ 384
#define C_ 3
#define K_ 4
#define IMG_PX (H_ * W_)
#define TILES_X 12            // 384/32
#define TILES_PER_IMG 144     // 12*12
#define GRID 9216             // 64 images * 144 tiles of 32x32

struct Tap { float v0, v1, v2; };   // 12B, dword-aligned -> global_load_dwordx3

__global__ __launch_bounds__(256, 2) void bilerp_kernel(
    const float* __restrict__ images,
    const float* __restrict__ theta,
    float* __restrict__ out)
{
    // bijective chunked XCD swizzle (GRID % 8 == 0): input L3/L2-resident
    int bid = blockIdx.x;
    int lbid = (bid & 7) * (GRID / 8) + (bid >> 3);

    int b  = lbid / TILES_PER_IMG;
    int t  = lbid - b * TILES_PER_IMG;
    int ti = t / TILES_X;
    int tj = t - ti * TILES_X;

    int wave = threadIdx.x >> 6;
    int lane = threadIdx.x & 63;
    int dy = lane >> 3;           // 8x8 lane tile: isotropic gather footprint
    int dx = lane & 7;

    int i_base = ti * 32 + (wave >> 1) * 16;
    int j_base = tj * 32 + (wave & 1) * 16;

    const float* th = theta + b * 6;
    float th0 = th[0], th1 = th[1], th2 = th[2];
    float th3 = th[3], th4 = th[4], th5 = th[5];
    const float* img = images + (size_t)b * (IMG_PX * C_);
    float* outb = out + (size_t)b * (IMG_PX * C_);

    const double STEP = 2.0 / 383.0;

    float wa_[K_], wb_[K_], wc_[K_], wd_[K_];
    Tap ta[K_], tb[K_], tc[K_], td[K_];
    int pi[K_], pj[K_];

    // ---- phase 1: addresses + all 16 gather loads ----
#pragma unroll
    for (int k = 0; k < K_; ++k) {
        int i = i_base + (k >> 1) * 8 + dy;
        int j = j_base + (k & 1) * 8 + dx;
        pi[k] = i; pj[k] = j;

        // numpy f32 linspace: f64 (k*step - 1) then cast; endpoint exact
        float xs = (j == W_ - 1) ? 1.0f : (float)((double)j * STEP - 1.0);
        float ys = (i == H_ - 1) ? 1.0f : (float)((double)i * STEP - 1.0);

        // einsum: ((th0*xs) + (th1*ys)) + th2 — per-op f32, no contraction
        float t0 = __fadd_rn(__fadd_rn(__fmul_rn(th0, xs), __fmul_rn(th1, ys)), th2);
        float t1 = __fadd_rn(__fadd_rn(__fmul_rn(th3, xs), __fmul_rn(th4, ys)), th5);

        float x = __fmul_rn(__fadd_rn(t0, 1.0f), (float)(W_ * 0.5));
        float y = __fmul_rn(__fadd_rn(t1, 1.0f), (float)(H_ * 0.5));

        float fx = floorf(x);
        float fy = floorf(y);
        int x0 = min(max((int)fx, 0), W_ - 1);
        int x1 = min(max((int)fx + 1, 0), W_ - 1);
        int y0 = min(max((int)fy, 0), H_ - 1);
        int y1 = min(max((int)fy + 1, 0), H_ - 1);

        float xc = fminf(fmaxf(x, 0.0f), (float)(W_ - 1));
        float yc = fminf(fmaxf(y, 0.0f), (float)(H_ - 1));

        float x0f = (float)x0, x1f = (float)x1;
        float y0f = (float)y0, y1f = (float)y1;

        float wx0 = __fsub_rn(x1f, xc);
        float wx1 = __fsub_rn(xc, x0f);
        float wy0 = __fsub_rn(y1f, yc);
        float wy1 = __fsub_rn(yc, y0f);

        wa_[k] = __fmul_rn(wx0, wy0);
        wb_[k] = __fmul_rn(wx0, wy1);
        wc_[k] = __fmul_rn(wx1, wy0);
        wd_[k] = __fmul_rn(wx1, wy1);

        ta[k] = *(const Tap*)(img + (y0 * W_ + x0) * C_);
        tb[k] = *(const Tap*)(img + (y1 * W_ + x0) * C_);
        tc[k] = *(const Tap*)(img + (y0 * W_ + x1) * C_);
        td[k] = *(const Tap*)(img + (y1 * W_ + x1) * C_);
    }

    // ---- phase 2: weighted sums (per-op rounded f32) + stores ----
#pragma unroll
    for (int k = 0; k < K_; ++k) {
        float r0 = __fadd_rn(
            __fadd_rn(
                __fadd_rn(__fmul_rn(wa_[k], ta[k].v0), __fmul_rn(wb_[k], tb[k].v0)),
                __fmul_rn(wc_[k], tc[k].v0)),
            __fmul_rn(wd_[k], td[k].v0));
        float r1 = __fadd_rn(
            __fadd_rn(
                __fadd_rn(__fmul_rn(wa_[k], ta[k].v1), __fmul_rn(wb_[k], tb[k].v1)),
                __fmul_rn(wc_[k], tc[k].v1)),
            __fmul_rn(wd_[k], td[k].v1));
        float r2 = __fadd_rn(
            __fadd_rn(
                __fadd_rn(__fmul_rn(wa_[k], ta[k].v2), __fmul_rn(wb_[k], tb[k].v2)),
                __fmul_rn(wc_[k], tc[k].v2)),
            __fmul_rn(wd_[k], td[k].v2));

        Tap* o = (Tap*)(outb + ((size_t)pi[k] * W_ + pj[k]) * C_);
        Tap v = { r0, r1, r2 };
        *o = v;
    }
}

extern "C" void kernel_launch(void* const* d_in, const int* in_sizes, int n_in,
                              void* d_out, int out_size, void* d_ws, size_t ws_size,
                              hipStream_t stream) {
    const float* images = (const float*)d_in[0];
    const float* theta  = (const float*)d_in[1];
    float* out = (float*)d_out;

    bilerp_kernel<<<GRID, 256, 0, stream>>>(images, theta, out);
}